// Round 9
// baseline (641.763 us; speedup 1.0000x reference)
//
#include <hip/hip_runtime.h>

typedef unsigned char u8;

#define TT 1024
#define BB 512
#define LL 50
#define STOPI 48
#define STARTI 49
#define NEGV -10000.0f

// ws layout:
//   [0, 2048)                  : int idx[512]
//   [4096, 4096+B*50*T)        : u8 ptr[B][50][T]   backpointers, [label][time]
//   [4096+B*50*T, +B*T*50*4)   : f32 vit[B][T][50]  per-step Viterbi rows
#define PTR_OFF   4096
#define PTR_BYTES ((size_t)BB * TT * LL)
#define VIT_OFF   (PTR_OFF + PTR_BYTES)

// ---- 50 named scalar transition weights (SSA, cannot be demoted to scratch)
#define FOR50(X) X(0) X(1) X(2) X(3) X(4) X(5) X(6) X(7) X(8) X(9) \
    X(10) X(11) X(12) X(13) X(14) X(15) X(16) X(17) X(18) X(19) \
    X(20) X(21) X(22) X(23) X(24) X(25) X(26) X(27) X(28) X(29) \
    X(30) X(31) X(32) X(33) X(34) X(35) X(36) X(37) X(38) X(39) \
    X(40) X(41) X(42) X(43) X(44) X(45) X(46) X(47) X(48) X(49)

#define DECL_TR(J) float tr##J = trans[lane * LL + (J)];
// volatile: cannot be deleted, duplicated, or rematerialized -> the value
// must live in a VGPR across the loop (rounds 2-7: non-volatile pin failed,
// VGPR_Count stayed 48 and the trans row was re-gathered every step)
#define PIN_TR(J) asm volatile("" : "+v"(tr##J));

// candidate score for 'from' j: broadcast vit[j] (SGPR) + resident tr_j
// NOTE: J must be a bare literal at every call site (token-paste tr##J).
#define AV(SRC, J) (__int_as_float(__builtin_amdgcn_readlane(                  \
                        __float_as_int(SRC), J)) + tr##J)

#define M3(A_, B_, C_) fmaxf(fmaxf((A_), (B_)), (C_))

// max over all 50 candidates: 4 independent max3 chains, no array live range
#define STEP_MAX(SRC, MOUT)                                                    \
    {                                                                          \
        float c0 = M3(AV(SRC,0),AV(SRC,1),AV(SRC,2));                          \
        c0 = M3(c0,AV(SRC,3),AV(SRC,4));   c0 = M3(c0,AV(SRC,5),AV(SRC,6));    \
        c0 = M3(c0,AV(SRC,7),AV(SRC,8));   c0 = M3(c0,AV(SRC,9),AV(SRC,10));   \
        c0 = M3(c0,AV(SRC,11),AV(SRC,12));                                     \
        float c1 = M3(AV(SRC,13),AV(SRC,14),AV(SRC,15));                       \
        c1 = M3(c1,AV(SRC,16),AV(SRC,17)); c1 = M3(c1,AV(SRC,18),AV(SRC,19));  \
        c1 = M3(c1,AV(SRC,20),AV(SRC,21)); c1 = M3(c1,AV(SRC,22),AV(SRC,23));  \
        c1 = M3(c1,AV(SRC,24),AV(SRC,25));                                     \
        float c2 = M3(AV(SRC,26),AV(SRC,27),AV(SRC,28));                       \
        c2 = M3(c2,AV(SRC,29),AV(SRC,30)); c2 = M3(c2,AV(SRC,31),AV(SRC,32));  \
        c2 = M3(c2,AV(SRC,33),AV(SRC,34)); c2 = M3(c2,AV(SRC,35),AV(SRC,36));  \
        c2 = fmaxf(c2,AV(SRC,37));                                             \
        float c3 = M3(AV(SRC,38),AV(SRC,39),AV(SRC,40));                       \
        c3 = M3(c3,AV(SRC,41),AV(SRC,42)); c3 = M3(c3,AV(SRC,43),AV(SRC,44));  \
        c3 = M3(c3,AV(SRC,45),AV(SRC,46)); c3 = M3(c3,AV(SRC,47),AV(SRC,48));  \
        c3 = fmaxf(c3,AV(SRC,49));                                             \
        (MOUT) = fmaxf(M3(c0,c1,c2), c3);                                      \
    }

// first-index argmax given the exact max M (bitwise one of the candidates):
// 4 independent min chains over { j : AV==M }. The AV() here CSE with
// STEP_MAX's (same SRC, same ops) -> no recompute cost.
// J is a bare literal everywhere (token-paste constraint).
#define EQC(SRC, M, J, CH) { int c_ = (AV(SRC,J) == (M)) ? (J) : 63;           \
                             CH = c_ < CH ? c_ : CH; }
#define STEP_ARG(SRC, M, IOUT)                                                 \
    {                                                                          \
        int ia = 63, ib = 63, ic = 63, id = 63;                                \
        EQC(SRC,M,0,ia)  EQC(SRC,M,1,ib)  EQC(SRC,M,2,ic)  EQC(SRC,M,3,id)     \
        EQC(SRC,M,4,ia)  EQC(SRC,M,5,ib)  EQC(SRC,M,6,ic)  EQC(SRC,M,7,id)     \
        EQC(SRC,M,8,ia)  EQC(SRC,M,9,ib)  EQC(SRC,M,10,ic) EQC(SRC,M,11,id)    \
        EQC(SRC,M,12,ia) EQC(SRC,M,13,ib) EQC(SRC,M,14,ic) EQC(SRC,M,15,id)    \
        EQC(SRC,M,16,ia) EQC(SRC,M,17,ib) EQC(SRC,M,18,ic) EQC(SRC,M,19,id)    \
        EQC(SRC,M,20,ia) EQC(SRC,M,21,ib) EQC(SRC,M,22,ic) EQC(SRC,M,23,id)    \
        EQC(SRC,M,24,ia) EQC(SRC,M,25,ib) EQC(SRC,M,26,ic) EQC(SRC,M,27,id)    \
        EQC(SRC,M,28,ia) EQC(SRC,M,29,ib) EQC(SRC,M,30,ic) EQC(SRC,M,31,id)    \
        EQC(SRC,M,32,ia) EQC(SRC,M,33,ib) EQC(SRC,M,34,ic) EQC(SRC,M,35,id)    \
        EQC(SRC,M,36,ia) EQC(SRC,M,37,ib) EQC(SRC,M,38,ic) EQC(SRC,M,39,id)    \
        EQC(SRC,M,40,ia) EQC(SRC,M,41,ib) EQC(SRC,M,42,ic) EQC(SRC,M,43,id)    \
        EQC(SRC,M,44,ia) EQC(SRC,M,45,ib) EQC(SRC,M,46,ic) EQC(SRC,M,47,id)    \
        EQC(SRC,M,48,ia) EQC(SRC,M,49,ib)                                      \
        const int q0 = ia < ib ? ia : ib;                                      \
        const int q1 = ic < id ? ic : id;                                      \
        (IOUT) = q0 < q1 ? q0 : q1;                                            \
    }

// ---------------------------------------------------------------------------
// K1: isolated serial max-only chain. One wave per batch, private SIMD,
// no LDS, no barriers. 50 scalar trans weights pinned resident.
// ---------------------------------------------------------------------------
__global__ __launch_bounds__(64, 1) void viterbi_max(
    const float* __restrict__ feats, const int* __restrict__ lens,
    const float* __restrict__ trans, float* __restrict__ out_scores,
    int* __restrict__ idx_ws, float* __restrict__ vit_ws)
{
    const int b    = blockIdx.x;
    const int lane = threadIdx.x;
    if (lane >= LL) return;                       // no barriers below; safe

    FOR50(DECL_TR)
    FOR50(PIN_TR)
    const float tr_stop = trans[STOPI * LL + lane];
    const int len = lens[b];

    float vit = (lane == STARTI) ? 0.0f : NEGV;

    const float* fb  = feats  + (size_t)b * (TT * LL);
    float*       vst = vit_ws + (size_t)b * (TT * LL);

    float f[8];                      // feats prefetch ring, depth 8
#pragma unroll
    for (int i = 0; i < 8; ++i) f[i] = fb[i * LL + lane];

    // guard-free full iterations: t = it*8+i < len for all i
    const int nfull = len >> 3;
    for (int it = 0; it < nfull; ++it) {
#pragma unroll
        for (int i = 0; i < 8; ++i) {
            const int t = (it << 3) + i;
            vst[(size_t)t * LL + lane] = vit;     // row t = pre-update vit
            float m; STEP_MAX(vit, m)
            vit = m + f[i];
            int tp = t + 8; if (tp > TT - 1) tp = TT - 1;
            f[i] = fb[(size_t)tp * LL + lane];    // prefetch t+8
        }
    }

    // tail: <= 7 guarded steps
    for (int t = nfull << 3; t < len; ++t) {
        vst[(size_t)t * LL + lane] = vit;
        float m; STEP_MAX(vit, m)
        vit = m + fb[(size_t)t * LL + lane];
    }

    // stop transition: exactly the t=len-1 update order (m+f)+tr_stop
    vit += tr_stop;

    // row 'len' (frozen, post-stop) for K2's r = min(t, len) lookup
    if (len < TT) vst[(size_t)len * LL + lane] = vit;

    // final score / first-index argmax (one-time)
    float m = -3.4e38f; int mi = 0;
#pragma unroll
    for (int j = 0; j < LL; ++j) {
        float s = __int_as_float(__builtin_amdgcn_readlane(__float_as_int(vit), j));
        if (s > m) { m = s; mi = j; }
    }
    if (lane == 0) { out_scores[b] = m; idx_ws[b] = mi; }
}

// ---------------------------------------------------------------------------
// K2: backpointer recompute, massively parallel. One wave per (b, 8-step
// group). Row loads hoisted (8 upfront, latency amortized); values bitwise
// identical to K1's; frozen rows dedupe via prev_r (wave-uniform branch).
// ---------------------------------------------------------------------------
__global__ __launch_bounds__(256, 2) void viterbi_ptr(
    const int* __restrict__ lens, const float* __restrict__ trans,
    const float* __restrict__ vit_ws, u8* __restrict__ ptr_ws)
{
    const int tid  = threadIdx.x;
    const int lane = tid & 63;
    if (lane >= LL) return;                        // no barriers below
    const int wid = (blockIdx.x << 2) | (tid >> 6);
    const int b   = wid >> 7;                      // 128 waves per batch
    const int t0  = (wid & 127) << 3;              // this wave's 8 steps

    FOR50(DECL_TR)
    FOR50(PIN_TR)
    const int len = lens[b];

    const float* vbase = vit_ws + (size_t)b * (TT * LL);
    u8* pt = ptr_ws + (size_t)b * (TT * LL) + (size_t)lane * TT;  // [to][t]

    float v[8];
#pragma unroll
    for (int g = 0; g < 8; ++g) {
        const int r = (t0 + g < len) ? (t0 + g) : len;
        v[g] = vbase[(size_t)r * LL + lane];
    }

    int prev_r = -1, cached = 0;
    unsigned pk0 = 0, pk1 = 0;
#pragma unroll
    for (int g = 0; g < 8; ++g) {
        const int t = t0 + g;
        const int r = (t < len) ? t : len;         // frozen rows collapse
        if (r != prev_r) {                         // wave-uniform
            prev_r = r;
            float m; STEP_MAX(v[g], m)
            STEP_ARG(v[g], m, cached)
        }
        if (g < 4) pk0 |= (unsigned)cached << (8 * g);
        else       pk1 |= (unsigned)cached << (8 * (g - 4));
    }
    *(unsigned*)(pt + t0)     = pk0;
    *(unsigned*)(pt + t0 + 4) = pk1;
}

// ---------------------------------------------------------------------------
// K3: backtrack with chunked pointer-jumping; XOR-swizzled LDS (passed r2/r7).
// byte (s,t) lives at (s<<10) + (t ^ ((s&31)<<2)).
// ---------------------------------------------------------------------------
#define LSW(S, T) (((S) << 10) + ((T) ^ (((S) & 31) << 2)))

__global__ __launch_bounds__(64) void viterbi_bwd(
    const int* __restrict__ idx_ws, const u8* __restrict__ ptr_ws,
    float* __restrict__ out_paths)
{
    const int b = blockIdx.x;
    const int lane = threadIdx.x;

    __shared__ u8 lptr[TT * LL];    // 51200 B, swizzled [label][t]
    __shared__ u8 maps[32 * LL];
    __shared__ int entries[33];

    {   // dword-level swizzled copy (XOR touches bits 0..4 of the dword index)
        const unsigned* src = (const unsigned*)(ptr_ws + (size_t)b * TT * LL);
        unsigned* dst = (unsigned*)lptr;
        for (int i = lane; i < (TT * LL) / 4; i += 64) {
            const int to = i >> 8;            // 256 dwords per label row
            const int t4 = i & 255;
            dst[(to << 8) + (t4 ^ (to & 31))] = src[i];
        }
    }
    __syncthreads();

    // phase 1: all 1600 (chunk, entry) walks; 25 chains per lane
    {
        int st[25], tt[25], cidx[25];
#pragma unroll
        for (int k = 0; k < 25; ++k) {
            int w = k * 64 + lane;
            int c = w / 50;
            int l = w - c * 50;
            st[k] = l;
            tt[k] = c * 32 + 31;
            cidx[k] = c * 50 + l;
        }
        for (int j = 0; j < 32; ++j) {
#pragma unroll
            for (int k = 0; k < 25; ++k) {
                st[k] = lptr[LSW(st[k], tt[k])];
                tt[k] -= 1;
            }
        }
#pragma unroll
        for (int k = 0; k < 25; ++k) maps[cidx[k]] = (u8)st[k];
    }
    __syncthreads();

    const int idx = idx_ws[b];

    // phase 2: compose chunk maps sequentially
    if (lane == 0) {
        int i = idx;
        for (int c = 31; c >= 0; --c) {
            entries[c + 1] = i;
            i = maps[c * 50 + i];
        }
        entries[0] = i;
    }
    __syncthreads();

    // phase 3: re-walk all 32 chunks in parallel, writing the path
    float* po = out_paths + (size_t)b * TT;
    if (lane < 32) {
        const int c = lane;
        int s = entries[c + 1];
        for (int j = 0; j < 32; ++j) {
            int t = c * 32 + 31 - j;
            int ni = lptr[LSW(s, t)];
            if (t > 0) po[t - 1] = (float)ni;
            s = ni;
        }
    }
    if (lane == 0) po[TT - 1] = (float)idx;
}

extern "C" void kernel_launch(void* const* d_in, const int* in_sizes, int n_in,
                              void* d_out, int out_size, void* d_ws, size_t ws_size,
                              hipStream_t stream) {
    const float* feats = (const float*)d_in[0];
    const int*   lens  = (const int*)d_in[1];
    const float* trans = (const float*)d_in[2];

    float* scores = (float*)d_out;          // [512]
    float* paths  = scores + BB;            // [512*1024]

    int*   idx_ws = (int*)d_ws;
    u8*    ptr_ws = (u8*)d_ws + PTR_OFF;
    float* vit_ws = (float*)((u8*)d_ws + VIT_OFF);

    viterbi_max<<<BB, 64, 0, stream>>>(feats, lens, trans, scores, idx_ws, vit_ws);
    viterbi_ptr<<<(BB * 128) / 4, 256, 0, stream>>>(lens, trans, vit_ws, ptr_ws);
    viterbi_bwd<<<BB, 64, 0, stream>>>(idx_ws, ptr_ws, paths);
}